// Round 1
// baseline (548.218 us; speedup 1.0000x reference)
//
#include <hip/hip_runtime.h>

// EmbeddingBagCollection: T=8 tables, B=4096 bags, L=50 lookups, V=100000, D=128.
// out[b, t*D + d] = sum_l tables[t, indices[t,b,l], d]
//
// One 32-lane group per bag: lane owns float4 (128 floats = 32 float4).
// Per gathered row: 32 lanes x 16B = 512B coalesced. 50 independent gathers
// per bag -> compiler pipelines global_load_dwordx4's to hide latency.
// Bags ordered t*B+b so resident blocks cluster on few tables (L3 locality).

#define T_ 8
#define B_ 4096
#define L_ 50
#define V_ 100000
#define D_ 128

__global__ __launch_bounds__(256) void EmbeddingBagCollection_56959856279962_kernel(
    const int* __restrict__ indices,   // [T, B, L] int32
    const float* __restrict__ tables,  // [T, V, D] f32
    float* __restrict__ out)           // [B, T*D] f32
{
    const int group = threadIdx.x >> 5;               // 0..7 (bag within block)
    const int lane  = threadIdx.x & 31;               // 0..31 (float4 within row)
    const int bag   = (blockIdx.x << 3) + group;      // 0..T_*B_-1, ordered t*B+b
    const int t = bag >> 12;                          // bag / B_
    const int b = bag & (B_ - 1);                     // bag % B_

    const int* __restrict__ idxp = indices + (size_t)bag * L_;
    const float* __restrict__ tbl = tables + (size_t)t * V_ * D_;

    float4 acc = make_float4(0.f, 0.f, 0.f, 0.f);
#pragma unroll 5
    for (int l = 0; l < L_; ++l) {
        const int idx = idxp[l];
        const float4* __restrict__ row =
            (const float4*)(tbl + (size_t)idx * D_);
        const float4 v = row[lane];
        acc.x += v.x; acc.y += v.y; acc.z += v.z; acc.w += v.w;
    }

    float4* __restrict__ op = (float4*)(out + (size_t)b * (T_ * D_) + (size_t)t * D_);
    op[lane] = acc;
}

extern "C" void kernel_launch(void* const* d_in, const int* in_sizes, int n_in,
                              void* d_out, int out_size, void* d_ws, size_t ws_size,
                              hipStream_t stream) {
    const int*   indices = (const int*)d_in[0];   // [T,B,L] int32 (harness converts)
    const float* tables  = (const float*)d_in[1]; // [T,V,D] f32
    float*       out     = (float*)d_out;         // [B, T*D] f32

    const int bags_per_block = 8;                 // 256 threads / 32-lane group
    const int grid = (T_ * B_) / bags_per_block;  // 4096 blocks
    EmbeddingBagCollection_56959856279962_kernel<<<grid, 256, 0, stream>>>(
        indices, tables, out);
}

// Round 3
// 537.989 us; speedup vs baseline: 1.0190x; 1.0190x over previous
//
#include <hip/hip_runtime.h>

// EmbeddingBagCollection: T=8 tables, B=4096 bags, L=50 lookups, V=100000, D=128.
// out[b, t*D + d] = sum_l tables[t, indices[t,b,l], d]
//
// One 32-lane group per bag: lane owns float4 (32 x 16B = one 512B row).
// Block = 256 threads = 8 bags. Grid = 4096 blocks, t-major bag order so the
// resident window stays within one 51.2MB table (fits 256MB L3 -> ~2x reuse).
//
// R3: fix R2's OOB — row stride is D*4 = 512 bytes => idx<<9 (R2 had <<11,
// reading 4x past the table => page fault). Keep: scalar table base
// (t is block-uniform), u32 per-lane offsets, CHUNK=10 index prefetch so 10
// independent row loads are in flight while next 10 indices load.

#define T_ 8
#define B_ 4096
#define L_ 50
#define V_ 100000
#define D_ 128
#define CHUNK 10

__global__ __launch_bounds__(256) void EmbeddingBagCollection_56959856279962_kernel(
    const int* __restrict__ indices,   // [T, B, L] int32
    const float* __restrict__ tables,  // [T, V, D] f32
    float* __restrict__ out)           // [B, T*D] f32
{
    const int group = threadIdx.x >> 5;               // bag within block
    const int lane  = threadIdx.x & 31;               // float4 within row
    const int bag0  = blockIdx.x << 3;                // first bag of block
    const int t     = bag0 >> 12;                     // block-uniform table id
    const int bag   = bag0 + group;
    const int b     = bag & (B_ - 1);

    const int* __restrict__ idxp = indices + bag * L_;
    const float* __restrict__ tbl = tables + (size_t)t * (V_ * D_); // scalar base

    float4 acc = make_float4(0.f, 0.f, 0.f, 0.f);

    int cur[CHUNK], nxt[CHUNK];
#pragma unroll
    for (int j = 0; j < CHUNK; ++j) cur[j] = idxp[j];

#pragma unroll
    for (int l = 0; l < L_; l += CHUNK) {
        if (l + CHUNK < L_) {
#pragma unroll
            for (int j = 0; j < CHUNK; ++j) nxt[j] = idxp[l + CHUNK + j];
        }
#pragma unroll
        for (int j = 0; j < CHUNK; ++j) {
            // row byte offset: idx * D * sizeof(float) = idx*512 -> <<9
            const unsigned off = ((unsigned)cur[j] << 9) | ((unsigned)lane << 4);
            const float4 v = *(const float4*)((const char*)tbl + off);
            acc.x += v.x; acc.y += v.y; acc.z += v.z; acc.w += v.w;
        }
#pragma unroll
        for (int j = 0; j < CHUNK; ++j) cur[j] = nxt[j];
    }

    float* __restrict__ op = out + b * (T_ * D_) + t * D_;
    ((float4*)op)[lane] = acc;
}

extern "C" void kernel_launch(void* const* d_in, const int* in_sizes, int n_in,
                              void* d_out, int out_size, void* d_ws, size_t ws_size,
                              hipStream_t stream) {
    const int*   indices = (const int*)d_in[0];   // [T,B,L] int32
    const float* tables  = (const float*)d_in[1]; // [T,V,D] f32
    float*       out     = (float*)d_out;         // [B, T*D] f32

    const int grid = (T_ * B_) / 8;               // 4096 blocks, 8 bags each
    EmbeddingBagCollection_56959856279962_kernel<<<grid, 256, 0, stream>>>(
        indices, tables, out);
}